// Round 2
// 98.654 us; speedup vs baseline: 1.1368x; 1.1368x over previous
//
#include <hip/hip_runtime.h>
#include <math.h>

#define NS 256000
#define N1 512            // FFT over n1: radix 8,8,8
#define N2 500            // FFT over n2: radices 5,5,5,4
#define PI_F 3.14159265358979323846f

typedef float2 cplx;

__device__ __forceinline__ cplx cadd(cplx a, cplx b){ return make_float2(a.x+b.x, a.y+b.y); }
__device__ __forceinline__ cplx csub(cplx a, cplx b){ return make_float2(a.x-b.x, a.y-b.y); }
__device__ __forceinline__ cplx cmul(cplx a, cplx b){ return make_float2(a.x*b.x-a.y*b.y, a.x*b.y+a.y*b.x); }
__device__ __forceinline__ cplx cmulc(cplx a, cplx b){ return make_float2(a.x*b.x+a.y*b.y, a.y*b.x-a.x*b.y); }
__device__ __forceinline__ cplx crotf(cplx v, float ang){
    float sn = __sinf(ang), cs = __cosf(ang);
    return make_float2(v.x*cs - v.y*sn, v.x*sn + v.y*cs);
}
// padded LDS index: +1 word every 16 elements -> <=2-way bank aliasing
__device__ __forceinline__ int PX(int e){ return e + (e>>4); }
// octal digit reversal of 9 bits (involution)
__device__ __forceinline__ int rev8_3(int k){ return ((k&7)<<6) | (k&0x38) | (k>>6); }

#define U1PAD 545   // >= PX(511)+1 = 543
#define U2PAD 537   // >= PX(499)+1 = 531
// wave-level LDS fence: columns are wave-private, no block barrier needed
#define WFENCE() asm volatile("s_waitcnt lgkmcnt(0)" ::: "memory")

template<bool INV>
__device__ __forceinline__ void dft4(const cplx* a, cplx* b){
    cplx t0=cadd(a[0],a[2]), t1=csub(a[0],a[2]), t2=cadd(a[1],a[3]), t3=csub(a[1],a[3]);
    b[0]=cadd(t0,t2); b[2]=csub(t0,t2);
    if(!INV){ b[1]=make_float2(t1.x+t3.y, t1.y-t3.x); b[3]=make_float2(t1.x-t3.y, t1.y+t3.x); }
    else    { b[1]=make_float2(t1.x-t3.y, t1.y+t3.x); b[3]=make_float2(t1.x+t3.y, t1.y-t3.x); }
}

template<bool INV>
__device__ __forceinline__ void dft8(const cplx* a, cplx* b){
    cplx ev[4]={a[0],a[2],a[4],a[6]}, od[4]={a[1],a[3],a[5],a[7]};
    cplx C[4], D[4];
    dft4<INV>(ev, C); dft4<INV>(od, D);
    const float s = 0.70710678118654752f;
    const float sg = INV ? 1.f : -1.f;
    cplx d1 = cmul(D[1], make_float2( s, sg*s));
    cplx d2 = cmul(D[2], make_float2(0.f, sg ));
    cplx d3 = cmul(D[3], make_float2(-s, sg*s));
    b[0]=cadd(C[0],D[0]); b[4]=csub(C[0],D[0]);
    b[1]=cadd(C[1],d1);   b[5]=csub(C[1],d1);
    b[2]=cadd(C[2],d2);   b[6]=csub(C[2],d2);
    b[3]=cadd(C[3],d3);   b[7]=csub(C[3],d3);
}

template<bool INV>
__device__ __forceinline__ void dft5(const cplx* a, cplx* b){
    const float c1=0.30901699437494742f, s1=0.95105651629515357f;
    const float c2=-0.80901699437494745f, s2=0.58778525229247312f;
    const float sg = INV ? 1.f : -1.f;
    cplx W[5];
    W[0]=make_float2(1.f,0.f);
    W[1]=make_float2(c1, sg*s1); W[2]=make_float2(c2, sg*s2);
    W[3]=make_float2(c2,-sg*s2); W[4]=make_float2(c1,-sg*s1);
#pragma unroll
    for(int u=0;u<5;++u){
        cplx acc = a[0];
        int idx = 0;
#pragma unroll
        for(int r=1;r<5;++r){
            idx += u; if(idx >= 5) idx -= 5;
            acc = cadd(acc, cmul(a[r], W[idx]));
        }
        b[u] = acc;
    }
}

// One in-place stage on a wave-private LDS column.
// Restructured: ALL butterfly reads issued first (one LDS-latency exposure),
// then compute, then all writes.  Butterfly element sets are disjoint, so the
// read-all/write-all reorder is exact.
template<int R, int L, int TMUL, bool INV, int NN>
__device__ __forceinline__ void wstage(cplx* Uw, const cplx* tab, int lane){
    constexpr int m = L / R;
    constexpr int nb = NN / R;
    constexpr int NIT = (nb + 63) / 64;
    cplx a[NIT][R];
    cplx wt[NIT][R];   // wt[][0] unused
    int  bs[NIT];
#pragma unroll
    for(int it=0; it<NIT; ++it){
        int beta = lane + it*64;
        int blk = beta / m;
        int j = beta - blk*m;
        bs[it] = blk*L + j;
        if(beta < nb){
#pragma unroll
            for(int t=0;t<R;++t) a[it][t] = Uw[PX(bs[it] + m*t)];
#pragma unroll
            for(int t=1;t<R;++t) wt[it][t] = tab[TMUL*j*t];
        }
    }
#pragma unroll
    for(int it=0; it<NIT; ++it){
        int beta = lane + it*64;
        if(beta < nb){
            if(INV){
#pragma unroll
                for(int t=1;t<R;++t) a[it][t] = cmulc(a[it][t], wt[it][t]);
            }
            cplx bb[R];
            if constexpr (R==4) dft4<INV>(a[it], bb);
            else if constexpr (R==5) dft5<INV>(a[it], bb);
            else dft8<INV>(a[it], bb);
            if(!INV){
#pragma unroll
                for(int t=1;t<R;++t) bb[t] = cmul(bb[t], wt[it][t]);
            }
#pragma unroll
            for(int t=0;t<R;++t) Uw[PX(bs[it] + m*t)] = bb[t];
        }
    }
}

template<int NTAB>
__device__ __forceinline__ void build_tab(cplx* tab, int tid){
    const float step = -2.f*PI_F/(float)NTAB;
    for(int i = tid; i < NTAB; i += 128){
        float a = step*(float)i;
        tab[i] = make_float2(__cosf(a), __sinf(a));
    }
}

// position p -> true k2 for the radix-(5,5,5,4) DIF order
__device__ __forceinline__ int p2k2(int p){
    int t1 = p/100; int r = p - 100*t1;
    int t2 = r/20;  r -= 20*t2;
    int t3 = r>>2;  int t4 = r & 3;
    return t1 + 5*t2 + 25*t3 + 125*t4;
}
// true k2 -> position p (inverse of p2k2)
__device__ __forceinline__ int k22p(int k){
    int t1 = k % 5; int k5 = k/5;
    int t2 = k5 % 5; int k25 = k5/5;
    int t3 = k25 % 5; int t4 = k25/5;
    return 100*t1 + 20*t2 + 4*t3 + t4;
}
// column-slot -> true k1.  Slots grouped so conjugate pairs (k1, 512-k1)
// share a block: blk 0 = {0, 256} (self-paired), blk j>=1 = {j, 512-j}.
__device__ __forceinline__ int colord(int q){
    int j = q>>1, w = q&1;
    if(j == 0) return w ? 256 : 0;
    return w ? 512 - j : j;
}
// bijective XCD-chunk swizzle (m204 variant): consecutive logical blocks on
// the same XCD so partial-cache-line writes merge in that XCD's L2.
__device__ __forceinline__ int xcd_chunk(int bid, int n){
    int q = n>>3, r = n&7;
    int x = bid&7, idx = bid>>3;
    return (x < r ? x*(q+1) : r*(q+1) + (x-r)*q) + idx;
}

// packed conjugate-pair filter: Z1=Z(k), Z2=Z(N-k) of FFT(xa + i*xb);
// ha/hb are the (real, symmetric) responses * 1/NS.
__device__ __forceinline__ void hpair(cplx Z1, cplx Z2, float ha, float hb,
                                      cplx* zk, cplx* znk){
    float xr = 0.5f*(Z1.x + Z2.x), xi = 0.5f*(Z1.y - Z2.y);   // Xa
    float yr = 0.5f*(Z1.y + Z2.y), yi = -0.5f*(Z1.x - Z2.x);  // Xb
    *zk  = make_float2(ha*xr - hb*yi, ha*xi + hb*yr);          // Ha*Xa + i*Hb*Xb
    *znk = make_float2(ha*xr + hb*yi, hb*yr - ha*xi);          // Ha*conj(Xa) + i*Hb*conj(Xb)
}

// ---------------------------------------------------------------------------
// K1: blocks 0..3 = frame-mean weights -> mm ; block 4 = logff table ;
// blocks 5.. = packed forward 512-FFT (2 signals x 500 n2-columns, wave/col),
// inter-pass twiddle, store in pair-grouped column order (coalesced).
// ---------------------------------------------------------------------------
__global__ void __launch_bounds__(128) kFused1(const float* __restrict__ fm,
                                               const float* __restrict__ noise,
                                               float* __restrict__ mmL,
                                               cplx* __restrict__ Y){
    __shared__ float Aarr[500];
    __shared__ float wfr[500];
    __shared__ float part[128];
    __shared__ cplx tab[512];
    __shared__ cplx U[2][U1PAD];
    const int bid = blockIdx.x, tid = threadIdx.x;
    if(bid < 4){
        const int b = bid;
        for(int f = tid; f < 500; f += 128){
            long long i0 = ((long long)f*255999LL + 498LL)/499LL;
            long long i1 = ((long long)(f+1)*255999LL + 498LL)/499LL;
            long long cnt = i1 - i0;
            long long sumi = (i0 + i1 - 1)*cnt/2;
            long long num = 499LL*sumi - cnt*(long long)f*255999LL;
            Aarr[f] = (float)((double)num / 255999.0);
        }
        __syncthreads();
        for(int f = tid; f < 500; f += 128){
            long long i0 = ((long long)f*255999LL + 498LL)/499LL;
            long long i1 = ((long long)(f+1)*255999LL + 498LL)/499LL;
            double w;
            if(f < 499) w = (double)(i1 - i0) - (double)Aarr[f] + (f > 0 ? (double)Aarr[f-1] : 0.0);
            else        w = (double)Aarr[498] + 1.0;
            wfr[f] = (float)(w / (double)NS);
        }
        __syncthreads();
        const int k = tid & 63, seg = tid >> 6;
        float acc = 0.f;
        for(int f = seg*250; f < seg*250 + 250; ++f)
            acc += wfr[f] * fm[(b*500 + f)*64 + k];
        part[seg*64 + k] = acc;
        __syncthreads();
        if(tid < 64) mmL[b*64 + tid] = part[tid] + part[64 + tid];
        return;
    }
    if(bid == 4){
        if(tid < 64){
            double a = log10(20.0), b2 = log10(11025.0);
            double e = a + (b2 - a)*(double)tid/63.0;
            float ff = (float)pow(10.0, e);
            mmL[256 + tid] = logf(ff + 1e-7f);
        }
        return;
    }
    // ---- packed forward 512-FFT part ----
    const int g = bid - 5;                 // [0,500)
    const int s = g / 250;                 // signal: (b0+i*b1) or (b2+i*b3)
    const int n2base = (g - s*250) * 2;
    const int lane = tid & 63, w = tid >> 6;
    build_tab<512>(tab, tid);
    const float* xa = noise + (size_t)(2*s)*NS + n2base;
    const float* xb = noise + (size_t)(2*s+1)*NS + n2base;
#pragma unroll
    for(int k=0;k<8;++k){
        int i = tid + 128*k;               // [0,1024)
        int n1 = i >> 1, ws = i & 1;
        U[ws][PX(n1)] = make_float2(xa[n1*500 + ws], xb[n1*500 + ws]);
    }
    __syncthreads();
    cplx* Uw = U[w];
    wstage<8,512, 1,false,512>(Uw, tab, lane); WFENCE();
    wstage<8, 64, 8,false,512>(Uw, tab, lane); WFENCE();
    wstage<8,  8,64,false,512>(Uw, tab, lane); WFENCE();
    const int n2 = n2base + w;
    cplx* yp = Y + ((size_t)s*500 + n2)*512;
    const float tw = -2.f*PI_F/(float)NS;
#pragma unroll
    for(int t=0;t<8;++t){
        int q = lane + 64*t;
        int c = colord(q);                 // true k1 stored at slot q
        cplx v = Uw[PX(rev8_3(c))];        // DIF order: bin c sits at pos rev8_3(c)
        v = crotf(v, tw*(float)(n2*c));
        yp[q] = v;
    }
}

// ---------------------------------------------------------------------------
// K2: per block one conjugate column pair (k1, 512-k1) of one packed signal:
// fwd 500-FFT, fused filter-response compute (replaces kT2+resp2), conjugate
// unpack -> filter -> repack, inv 500-FFT, inv twiddle.  In-place on Y.
// grid = 2 signals x 256 pair-blocks = 512.
// ---------------------------------------------------------------------------
__global__ void __launch_bounds__(128) kFused2(cplx* __restrict__ Y,
                                               const float* __restrict__ mmL){
    __shared__ cplx tab[500];
    __shared__ cplx U[2][U2PAD];
    __shared__ float Hr[4][500];
    __shared__ float mmS[2][64];
    __shared__ float lgf[64];
    const int tid = threadIdx.x, lane = tid & 63, w = tid >> 6;
    const int L = xcd_chunk(blockIdx.x, 512);
    const int s = L >> 8, blk = L & 255;
    build_tab<500>(tab, tid);
    if(tid < 128) mmS[tid>>6][tid&63] = mmL[2*s*64 + tid];
    if(tid < 64)  lgf[tid] = mmL[256 + tid];
    cplx* yb = Y + (size_t)s*500*512 + 2*blk;
    // stage column loads into registers; response compute overlaps the latency
    cplx rg[8];
#pragma unroll
    for(int k=0;k<8;++k){
        int i = tid + 128*k;
        rg[k] = (i < 1000) ? yb[(i>>1)*512 + (i&1)] : make_float2(0.f, 0.f);
    }
    __syncthreads();                       // mmS/lgf/tab visible
    // fused filter response for this block's k1 row(s); H(N-k)=H(k) so only
    // rows k1<=256 are ever needed.  Hr already includes the 1/NS scale.
    const int nrows = (blk == 0) ? 2 : 1;
    const float invN = 1.f/(float)NS;
    for(int idx = tid; idx < nrows*500; idx += 128){
        int r = (idx >= 500) ? 1 : 0;
        int p = idx - 500*r;
        int k1 = (blk == 0) ? (r ? 256 : 0) : blk;
        int k2 = p2k2(p);
        int kf = k1 + 512*k2;
        int kk = min(kf, NS - kf);
        float lf = logf((float)kk*(22050.f/(float)NS) + 1e-7f);
        float wsum = 0.f, a0 = 0.f, a1 = 0.f;
#pragma unroll
        for(int jb=0;jb<64;++jb){
            float d = lf - lgf[jb];
            float e = __expf(-2.f*d*d);
            wsum += e; a0 += e*mmS[0][jb]; a1 += e*mmS[1][jb];
        }
        float inv = invN/(wsum + 1e-7f);
        Hr[2*r  ][p] = a0*inv;
        Hr[2*r+1][p] = a1*inv;
    }
#pragma unroll
    for(int k=0;k<8;++k){
        int i = tid + 128*k;
        if(i < 1000) U[i&1][PX(i>>1)] = rg[k];
    }
    __syncthreads();
    cplx* Uw = U[w];
    wstage<5,500,  1,false,500>(Uw, tab, lane); WFENCE();
    wstage<5,100,  5,false,500>(Uw, tab, lane); WFENCE();
    wstage<5, 20, 25,false,500>(Uw, tab, lane); WFENCE();
    wstage<4,  4,125,false,500>(Uw, tab, lane); WFENCE();
    __syncthreads();
    // ---- conjugate-pair unpack -> filter -> repack ----
    // partner of position p (k2 digit-complement) is position 499-p.
    if(blk == 0){
        if(w == 0){
            // column k1=0, self-paired: partner k2' = (500-k2)%500
#pragma unroll
            for(int t=0;t<8;++t){
                int p = lane + 64*t;
                if(p < 500){
                    int k2 = p2k2(p);
                    int pp = k22p((500 - k2) % 500);
                    if(p <= pp){
                        cplx Z1 = U[0][PX(p)], Z2 = U[0][PX(pp)];
                        cplx zk, znk;
                        hpair(Z1, Z2, Hr[0][p], Hr[1][p], &zk, &znk);
                        U[0][PX(p)]  = zk;
                        U[0][PX(pp)] = znk;
                    }
                }
            }
        } else {
            // column k1=256, self-paired: partner position 499-p
#pragma unroll
            for(int t=0;t<4;++t){
                int p = lane + 64*t;
                if(p < 250){
                    cplx Z1 = U[1][PX(p)], Z2 = U[1][PX(499-p)];
                    cplx zk, znk;
                    hpair(Z1, Z2, Hr[2][p], Hr[3][p], &zk, &znk);
                    U[1][PX(p)]     = zk;
                    U[1][PX(499-p)] = znk;
                }
            }
        }
    } else {
        // cross pair: (col blk, pos p) <-> (col 512-blk, pos 499-p), all p.
        // wave0: p in [0,250), wave1: p in [250,500) -> disjoint writes.
#pragma unroll
        for(int t=0;t<4;++t){
            int pl = lane + 64*t;
            if(pl < 250){
                int p = w*250 + pl;
                cplx Z1 = U[0][PX(p)], Z2 = U[1][PX(499-p)];
                cplx zk, znk;
                hpair(Z1, Z2, Hr[0][p], Hr[1][p], &zk, &znk);
                U[0][PX(p)]     = zk;
                U[1][PX(499-p)] = znk;
            }
        }
    }
    __syncthreads();
    wstage<4,  4,125,true,500>(Uw, tab, lane); WFENCE();
    wstage<5, 20, 25,true,500>(Uw, tab, lane); WFENCE();
    wstage<5,100,  5,true,500>(Uw, tab, lane); WFENCE();
    wstage<5,500,  1,true,500>(Uw, tab, lane); WFENCE();
    __syncthreads();
    const float tw = 2.f*PI_F/(float)NS;
#pragma unroll
    for(int k=0;k<8;++k){
        int i = tid + 128*k;
        if(i < 1000){
            int n2 = i >> 1, ws = i & 1;
            int c = colord(2*blk + ws);
            cplx v = U[ws][PX(n2)];
            v = crotf(v, tw*(float)(n2*c));
            yb[n2*512 + ws] = v;
        }
    }
}

// ---------------------------------------------------------------------------
// K3: inverse 512-FFT per (signal, n2) column; Re -> batch 2s, Im -> 2s+1.
// grid = 2 signals x 250 column-pairs = 500 (XCD-chunked for write merging).
// ---------------------------------------------------------------------------
__global__ void __launch_bounds__(128) kFused3(const cplx* __restrict__ Y,
                                               float* __restrict__ out){
    __shared__ cplx tab[512];
    __shared__ cplx U[2][U1PAD];
    const int tid = threadIdx.x, lane = tid & 63, w = tid >> 6;
    const int L = xcd_chunk(blockIdx.x, 500);
    const int s = L / 250;
    const int n2base = (L - s*250) * 2;
    build_tab<512>(tab, tid);
    const cplx* yp = Y + ((size_t)s*500 + n2base)*512;
#pragma unroll
    for(int k=0;k<8;++k){
        int i = tid + 128*k;               // [0,1024)
        int ws = i >> 9, q = i & 511;      // coalesced in q
        cplx v = yp[(size_t)ws*512 + q];
        U[ws][PX(rev8_3(colord(q)))] = v;  // bin c -> DIT position rev8_3(c)
    }
    __syncthreads();
    cplx* Uw = U[w];
    wstage<8,  8,64,true,512>(Uw, tab, lane); WFENCE();
    wstage<8, 64, 8,true,512>(Uw, tab, lane); WFENCE();
    wstage<8,512, 1,true,512>(Uw, tab, lane); WFENCE();
    __syncthreads();
    float* oa = out + (size_t)(2*s)*NS + n2base;
    float* ob = out + (size_t)(2*s+1)*NS + n2base;
#pragma unroll
    for(int k=0;k<8;++k){
        int i = tid + 128*k;
        int n1 = i >> 1, ws = i & 1;
        cplx v = U[ws][PX(n1)];
        oa[n1*500 + ws] = v.x;
        ob[n1*500 + ws] = v.y;
    }
}

// ---------------------------------------------------------------------------
extern "C" void kernel_launch(void* const* d_in, const int* in_sizes, int n_in,
                              void* d_out, int out_size, void* d_ws, size_t ws_size,
                              hipStream_t stream) {
    const float* fm = (const float*)d_in[0];     // (4,500,64)
    const float* noise = (const float*)d_in[1];  // (4,256000)
    float* out = (float*)d_out;

    char* ws = (char*)d_ws;
    cplx*  Y   = (cplx*)ws;                      // 2 signals * 256000 cplx = 4,096,000 B
    float* mmL = (float*)(ws + 4200000);         // mm[4][64] + logff[64] = 1,280 B

    kFused1<<<505, 128, 0, stream>>>(fm, noise, mmL, Y);
    kFused2<<<512, 128, 0, stream>>>(Y, mmL);
    kFused3<<<500, 128, 0, stream>>>(Y, out);
}

// Round 3
// 93.453 us; speedup vs baseline: 1.2000x; 1.0557x over previous
//
#include <hip/hip_runtime.h>
#include <math.h>

#define NS 256000
#define N1 512            // FFT over n1: radix 8,8,8
#define N2 500            // FFT over n2: radices 5,5,5,4
#define PI_F 3.14159265358979323846f

typedef float2 cplx;

__device__ __forceinline__ cplx cadd(cplx a, cplx b){ return make_float2(a.x+b.x, a.y+b.y); }
__device__ __forceinline__ cplx csub(cplx a, cplx b){ return make_float2(a.x-b.x, a.y-b.y); }
__device__ __forceinline__ cplx cmul(cplx a, cplx b){ return make_float2(a.x*b.x-a.y*b.y, a.x*b.y+a.y*b.x); }
__device__ __forceinline__ cplx cmulc(cplx a, cplx b){ return make_float2(a.x*b.x+a.y*b.y, a.y*b.x-a.x*b.y); }
__device__ __forceinline__ cplx crotf(cplx v, float ang){
    float sn = __sinf(ang), cs = __cosf(ang);
    return make_float2(v.x*cs - v.y*sn, v.x*sn + v.y*cs);
}
// padded LDS index: +1 word every 16 elements -> <=2-way bank aliasing
__device__ __forceinline__ int PX(int e){ return e + (e>>4); }
// octal digit reversal of 9 bits (involution)
__device__ __forceinline__ int rev8_3(int k){ return ((k&7)<<6) | (k&0x38) | (k>>6); }

#define U1PAD 545   // >= PX(511)+1 = 543
#define U2PAD 537   // >= PX(499)+1 = 531
// wave-level LDS fence: wave-private columns, no block barrier needed
#define WFENCE() asm volatile("s_waitcnt lgkmcnt(0)" ::: "memory")
// LDS-only block barrier: does NOT drain vmcnt, so global loads stay in flight
#define LDS_BARRIER() do{ asm volatile("s_waitcnt lgkmcnt(0)" ::: "memory"); __builtin_amdgcn_s_barrier(); }while(0)

template<bool INV>
__device__ __forceinline__ void dft4(const cplx* a, cplx* b){
    cplx t0=cadd(a[0],a[2]), t1=csub(a[0],a[2]), t2=cadd(a[1],a[3]), t3=csub(a[1],a[3]);
    b[0]=cadd(t0,t2); b[2]=csub(t0,t2);
    if(!INV){ b[1]=make_float2(t1.x+t3.y, t1.y-t3.x); b[3]=make_float2(t1.x-t3.y, t1.y+t3.x); }
    else    { b[1]=make_float2(t1.x-t3.y, t1.y+t3.x); b[3]=make_float2(t1.x+t3.y, t1.y-t3.x); }
}

template<bool INV>
__device__ __forceinline__ void dft8(const cplx* a, cplx* b){
    cplx ev[4]={a[0],a[2],a[4],a[6]}, od[4]={a[1],a[3],a[5],a[7]};
    cplx C[4], D[4];
    dft4<INV>(ev, C); dft4<INV>(od, D);
    const float s = 0.70710678118654752f;
    const float sg = INV ? 1.f : -1.f;
    cplx d1 = cmul(D[1], make_float2( s, sg*s));
    cplx d2 = cmul(D[2], make_float2(0.f, sg ));
    cplx d3 = cmul(D[3], make_float2(-s, sg*s));
    b[0]=cadd(C[0],D[0]); b[4]=csub(C[0],D[0]);
    b[1]=cadd(C[1],d1);   b[5]=csub(C[1],d1);
    b[2]=cadd(C[2],d2);   b[6]=csub(C[2],d2);
    b[3]=cadd(C[3],d3);   b[7]=csub(C[3],d3);
}

template<bool INV>
__device__ __forceinline__ void dft5(const cplx* a, cplx* b){
    const float c1=0.30901699437494742f, s1=0.95105651629515357f;
    const float c2=-0.80901699437494745f, s2=0.58778525229247312f;
    const float sg = INV ? 1.f : -1.f;
    cplx W[5];
    W[0]=make_float2(1.f,0.f);
    W[1]=make_float2(c1, sg*s1); W[2]=make_float2(c2, sg*s2);
    W[3]=make_float2(c2,-sg*s2); W[4]=make_float2(c1,-sg*s1);
#pragma unroll
    for(int u=0;u<5;++u){
        cplx acc = a[0];
        int idx = 0;
#pragma unroll
        for(int r=1;r<5;++r){
            idx += u; if(idx >= 5) idx -= 5;
            acc = cadd(acc, cmul(a[r], W[idx]));
        }
        b[u] = acc;
    }
}

// wave-private in-place stage (K1/K3): all reads first, then compute+write.
template<int R, int L, int TMUL, bool INV, int NN>
__device__ __forceinline__ void wstage(cplx* Uw, const cplx* tab, int lane){
    constexpr int m = L / R;
    constexpr int nb = NN / R;
    constexpr int NIT = (nb + 63) / 64;
    cplx a[NIT][R];
    cplx wt[NIT][R];   // wt[][0] unused
    int  bs[NIT];
#pragma unroll
    for(int it=0; it<NIT; ++it){
        int beta = lane + it*64;
        int blk = beta / m;
        int j = beta - blk*m;
        bs[it] = blk*L + j;
        if(beta < nb){
#pragma unroll
            for(int t=0;t<R;++t) a[it][t] = Uw[PX(bs[it] + m*t)];
#pragma unroll
            for(int t=1;t<R;++t) wt[it][t] = tab[TMUL*j*t];
        }
    }
#pragma unroll
    for(int it=0; it<NIT; ++it){
        int beta = lane + it*64;
        if(beta < nb){
            if(INV){
#pragma unroll
                for(int t=1;t<R;++t) a[it][t] = cmulc(a[it][t], wt[it][t]);
            }
            cplx bb[R];
            if constexpr (R==4) dft4<INV>(a[it], bb);
            else if constexpr (R==5) dft5<INV>(a[it], bb);
            else dft8<INV>(a[it], bb);
            if(!INV){
#pragma unroll
                for(int t=1;t<R;++t) bb[t] = cmul(bb[t], wt[it][t]);
            }
#pragma unroll
            for(int t=0;t<R;++t) Uw[PX(bs[it] + m*t)] = bb[t];
        }
    }
}

// 2-wave cooperative stage on one 500-pt column (K2): wave half h covers
// beta in [h*HB, ...). Caller must __syncthreads() between stages.
template<int R, int L, int TMUL, bool INV>
__device__ __forceinline__ void wstage2(cplx* Uc, const cplx* tab, int lane, int h){
    constexpr int m = L / R;
    constexpr int nb = 500 / R;
    constexpr int HB = (nb + 1) / 2;
    const int lim = h ? (nb - HB) : HB;
    if(lane < lim){
        int beta = h*HB + lane;
        int blk = beta / m;
        int j = beta - blk*m;
        int base = blk*L + j;
        cplx a[R];
#pragma unroll
        for(int t=0;t<R;++t) a[t] = Uc[PX(base + m*t)];
        cplx wt[R];
#pragma unroll
        for(int t=1;t<R;++t) wt[t] = tab[TMUL*j*t];
        if(INV){
#pragma unroll
            for(int t=1;t<R;++t) a[t] = cmulc(a[t], wt[t]);
        }
        cplx bb[R];
        if constexpr (R==4) dft4<INV>(a,bb);
        else if constexpr (R==5) dft5<INV>(a,bb);
        else dft8<INV>(a,bb);
        if(!INV){
#pragma unroll
            for(int t=1;t<R;++t) bb[t] = cmul(bb[t], wt[t]);
        }
#pragma unroll
        for(int t=0;t<R;++t) Uc[PX(base + m*t)] = bb[t];
    }
}

template<int NTAB, int NTHR>
__device__ __forceinline__ void build_tab(cplx* tab, int tid){
    const float step = -2.f*PI_F/(float)NTAB;
    for(int i = tid; i < NTAB; i += NTHR){
        float a = step*(float)i;
        tab[i] = make_float2(__cosf(a), __sinf(a));
    }
}

// position p -> true k2 for the radix-(5,5,5,4) DIF order
__device__ __forceinline__ int p2k2(int p){
    int t1 = p/100; int r = p - 100*t1;
    int t2 = r/20;  r -= 20*t2;
    int t3 = r>>2;  int t4 = r & 3;
    return t1 + 5*t2 + 25*t3 + 125*t4;
}
// true k2 -> position p (inverse of p2k2)
__device__ __forceinline__ int k22p(int k){
    int t1 = k % 5; int k5 = k/5;
    int t2 = k5 % 5; int k25 = k5/5;
    int t3 = k25 % 5; int t4 = k25/5;
    return 100*t1 + 20*t2 + 4*t3 + t4;
}
// column-slot -> true k1.  Slots grouped so conjugate pairs (k1, 512-k1)
// share a block: blk 0 = {0, 256} (self-paired), blk j>=1 = {j, 512-j}.
__device__ __forceinline__ int colord(int q){
    int j = q>>1, w = q&1;
    if(j == 0) return w ? 256 : 0;
    return w ? 512 - j : j;
}
// bijective XCD-chunk swizzle
__device__ __forceinline__ int xcd_chunk(int bid, int n){
    int q = n>>3, r = n&7;
    int x = bid&7, idx = bid>>3;
    return (x < r ? x*(q+1) : r*(q+1) + (x-r)*q) + idx;
}

// packed conjugate-pair filter
__device__ __forceinline__ void hpair(cplx Z1, cplx Z2, float ha, float hb,
                                      cplx* zk, cplx* znk){
    float xr = 0.5f*(Z1.x + Z2.x), xi = 0.5f*(Z1.y - Z2.y);   // Xa
    float yr = 0.5f*(Z1.y + Z2.y), yi = -0.5f*(Z1.x - Z2.x);  // Xb
    *zk  = make_float2(ha*xr - hb*yi, ha*xi + hb*yr);
    *znk = make_float2(ha*xr + hb*yi, hb*yr - ha*xi);
}

// ---------------------------------------------------------------------------
// K1: blocks 0..3 = frame-mean weights; block 4 = logff; blocks 5.. = packed
// forward 512-FFT, 4 n2-columns per 4-wave block (wave-per-column).
// ---------------------------------------------------------------------------
__global__ void __launch_bounds__(256) kFused1(const float* __restrict__ fm,
                                               const float* __restrict__ noise,
                                               float* __restrict__ mmL,
                                               cplx* __restrict__ Y){
    __shared__ float Aarr[500];
    __shared__ float wfr[500];
    __shared__ float part[256];
    __shared__ cplx tab[512];
    __shared__ cplx U[4][U1PAD];
    const int bid = blockIdx.x, tid = threadIdx.x;
    if(bid < 4){
        const int b = bid;
        for(int f = tid; f < 500; f += 256){
            long long i0 = ((long long)f*255999LL + 498LL)/499LL;
            long long i1 = ((long long)(f+1)*255999LL + 498LL)/499LL;
            long long cnt = i1 - i0;
            long long sumi = (i0 + i1 - 1)*cnt/2;
            long long num = 499LL*sumi - cnt*(long long)f*255999LL;
            Aarr[f] = (float)((double)num / 255999.0);
        }
        __syncthreads();
        for(int f = tid; f < 500; f += 256){
            long long i0 = ((long long)f*255999LL + 498LL)/499LL;
            long long i1 = ((long long)(f+1)*255999LL + 498LL)/499LL;
            double w;
            if(f < 499) w = (double)(i1 - i0) - (double)Aarr[f] + (f > 0 ? (double)Aarr[f-1] : 0.0);
            else        w = (double)Aarr[498] + 1.0;
            wfr[f] = (float)(w / (double)NS);
        }
        __syncthreads();
        const int k = tid & 63, seg = tid >> 6;
        float acc = 0.f;
        for(int f = seg*125; f < seg*125 + 125; ++f)
            acc += wfr[f] * fm[(b*500 + f)*64 + k];
        part[seg*64 + k] = acc;
        __syncthreads();
        if(tid < 64) mmL[b*64 + tid] = part[tid] + part[64+tid] + part[128+tid] + part[192+tid];
        return;
    }
    if(bid == 4){
        if(tid < 64){
            double a = log10(20.0), b2 = log10(11025.0);
            double e = a + (b2 - a)*(double)tid/63.0;
            float ff = (float)pow(10.0, e);
            mmL[256 + tid] = logf(ff + 1e-7f);
        }
        return;
    }
    // ---- packed forward 512-FFT: 4 columns per block ----
    const int g = xcd_chunk(bid - 5, 250);     // [0,250)
    const int s = g / 125;                     // signal
    const int n2base = (g - s*125) * 4;
    const int lane = tid & 63, w = tid >> 6;
    build_tab<512,256>(tab, tid);
    const float* xa = noise + (size_t)(2*s)*NS + n2base;
    const float* xb = noise + (size_t)(2*s+1)*NS + n2base;
#pragma unroll
    for(int k=0;k<8;++k){
        int i = tid + 256*k;                   // [0,2048)
        int n1 = i >> 2, ws = i & 3;
        U[ws][PX(n1)] = make_float2(xa[n1*500 + ws], xb[n1*500 + ws]);
    }
    __syncthreads();
    cplx* Uw = U[w];
    wstage<8,512, 1,false,512>(Uw, tab, lane); WFENCE();
    wstage<8, 64, 8,false,512>(Uw, tab, lane); WFENCE();
    wstage<8,  8,64,false,512>(Uw, tab, lane); WFENCE();
    const int n2 = n2base + w;
    cplx* yp = Y + ((size_t)s*500 + n2)*512;
    const float tw = -2.f*PI_F/(float)NS;
#pragma unroll
    for(int t=0;t<8;++t){
        int q = lane + 64*t;
        int c = colord(q);
        cplx v = Uw[PX(rev8_3(c))];
        v = crotf(v, tw*(float)(n2*c));
        yp[q] = v;
    }
}

// ---------------------------------------------------------------------------
// K2: one conjugate column pair per 4-wave block; 2 waves cooperate per
// 500-pt column (8 waves/CU).  Global loads overlap the Hr/exp compute via
// an LDS-only barrier.  In-place on Y.  grid = 512.
// ---------------------------------------------------------------------------
__global__ void __launch_bounds__(256) kFused2(cplx* __restrict__ Y,
                                               const float* __restrict__ mmL){
    __shared__ cplx tab[500];
    __shared__ cplx U[2][U2PAD];
    __shared__ float Hr[4][500];
    __shared__ float mmS[2][64];
    __shared__ float lgf[64];
    const int tid = threadIdx.x, lane = tid & 63, W = tid >> 6;
    const int L = xcd_chunk(blockIdx.x, 512);
    const int s = L >> 8, blk = L & 255;
    cplx* yb = Y + (size_t)s*500*512 + 2*blk;
    // issue global loads FIRST; they stay in flight through the Hr compute
    cplx rg[4];
#pragma unroll
    for(int k=0;k<4;++k){
        int i = tid + 256*k;
        rg[k] = (i < 1000) ? yb[(i>>1)*512 + (i&1)] : make_float2(0.f, 0.f);
    }
    build_tab<500,256>(tab, tid);
    if(tid < 128) mmS[tid>>6][tid&63] = mmL[2*s*64 + tid];
    if(tid < 64)  lgf[tid] = mmL[256 + tid];
    LDS_BARRIER();                        // mmS/lgf/tab visible; vmem NOT drained
    // fused filter response (H(N-k)=H(k): only k1<=256 rows exist).
    const int nrows = (blk == 0) ? 2 : 1;
    const float invN = 1.f/(float)NS;
    for(int idx = tid; idx < nrows*500; idx += 256){
        int r = (idx >= 500) ? 1 : 0;
        int p = idx - 500*r;
        int k1 = (blk == 0) ? (r ? 256 : 0) : blk;
        int k2 = p2k2(p);
        int kf = k1 + 512*k2;
        int kk = min(kf, NS - kf);
        float lf = logf((float)kk*(22050.f/(float)NS) + 1e-7f);
        float wsum = 0.f, a0 = 0.f, a1 = 0.f;
#pragma unroll
        for(int jb=0;jb<64;++jb){
            float d = lf - lgf[jb];
            float e = __expf(-2.f*d*d);
            wsum += e; a0 += e*mmS[0][jb]; a1 += e*mmS[1][jb];
        }
        float inv = invN/(wsum + 1e-7f);
        Hr[0][p] = (r==0) ? a0*inv : Hr[0][p];
        // (write via straight stores; conditional-select form avoids races)
        if(r==0){ Hr[0][p] = a0*inv; Hr[1][p] = a1*inv; }
        else    { Hr[2][p] = a0*inv; Hr[3][p] = a1*inv; }
    }
    // park loads into LDS (compiler inserts the vmcnt waits here)
#pragma unroll
    for(int k=0;k<4;++k){
        int i = tid + 256*k;
        if(i < 1000) U[i&1][PX(i>>1)] = rg[k];
    }
    __syncthreads();
    const int c = W >> 1, h = W & 1;
    cplx* Uc = U[c];
    wstage2<5,500,  1,false>(Uc, tab, lane, h); __syncthreads();
    wstage2<5,100,  5,false>(Uc, tab, lane, h); __syncthreads();
    wstage2<5, 20, 25,false>(Uc, tab, lane, h); __syncthreads();
    wstage2<4,  4,125,false>(Uc, tab, lane, h); __syncthreads();
    // ---- conjugate-pair unpack -> filter -> repack ----
    if(blk == 0){
        if(c == 0){
            // column k1=0, self-paired: partner k2' = (500-k2)%500
#pragma unroll
            for(int t=0;t<4;++t){
                int p = h*250 + lane + 64*t;
                if(lane + 64*t < 250){
                    int k2 = p2k2(p);
                    int pp = k22p((500 - k2) % 500);
                    if(p <= pp){
                        cplx Z1 = U[0][PX(p)], Z2 = U[0][PX(pp)];
                        cplx zk, znk;
                        hpair(Z1, Z2, Hr[0][p], Hr[1][p], &zk, &znk);
                        U[0][PX(p)]  = zk;
                        U[0][PX(pp)] = znk;
                    }
                }
            }
        } else {
            // column k1=256, self-paired: partner position 499-p
#pragma unroll
            for(int t=0;t<2;++t){
                int pl = lane + 64*t;
                if(pl < 125){
                    int p = h*125 + pl;
                    cplx Z1 = U[1][PX(p)], Z2 = U[1][PX(499-p)];
                    cplx zk, znk;
                    hpair(Z1, Z2, Hr[2][p], Hr[3][p], &zk, &znk);
                    U[1][PX(p)]     = zk;
                    U[1][PX(499-p)] = znk;
                }
            }
        }
    } else {
        // cross pair: (col blk, p) <-> (col 512-blk, 499-p); 4 waves x 125 p
#pragma unroll
        for(int t=0;t<2;++t){
            int pl = lane + 64*t;
            if(pl < 125){
                int p = W*125 + pl;
                cplx Z1 = U[0][PX(p)], Z2 = U[1][PX(499-p)];
                cplx zk, znk;
                hpair(Z1, Z2, Hr[0][p], Hr[1][p], &zk, &znk);
                U[0][PX(p)]     = zk;
                U[1][PX(499-p)] = znk;
            }
        }
    }
    __syncthreads();
    wstage2<4,  4,125,true>(Uc, tab, lane, h); __syncthreads();
    wstage2<5, 20, 25,true>(Uc, tab, lane, h); __syncthreads();
    wstage2<5,100,  5,true>(Uc, tab, lane, h); __syncthreads();
    wstage2<5,500,  1,true>(Uc, tab, lane, h); __syncthreads();
    const float tw = 2.f*PI_F/(float)NS;
#pragma unroll
    for(int k=0;k<4;++k){
        int i = tid + 256*k;
        if(i < 1000){
            int n2 = i >> 1, ws = i & 1;
            int cc = colord(2*blk + ws);
            cplx v = U[ws][PX(n2)];
            v = crotf(v, tw*(float)(n2*cc));
            yb[n2*512 + ws] = v;
        }
    }
}

// ---------------------------------------------------------------------------
// K3: inverse 512-FFT; 4 n2-columns per 4-wave block (wave-per-column).
// Re -> batch 2s, Im -> batch 2s+1.  grid = 250.
// ---------------------------------------------------------------------------
__global__ void __launch_bounds__(256) kFused3(const cplx* __restrict__ Y,
                                               float* __restrict__ out){
    __shared__ cplx tab[512];
    __shared__ cplx U[4][U1PAD];
    const int tid = threadIdx.x, lane = tid & 63, w = tid >> 6;
    const int g = xcd_chunk(blockIdx.x, 250);
    const int s = g / 125;
    const int n2base = (g - s*125) * 4;
    build_tab<512,256>(tab, tid);
    const cplx* yp = Y + ((size_t)s*500 + n2base)*512;
#pragma unroll
    for(int k=0;k<8;++k){
        int i = tid + 256*k;                   // [0,2048)
        int ws = i >> 9, q = i & 511;          // coalesced in q
        cplx v = yp[(size_t)ws*512 + q];
        U[ws][PX(rev8_3(colord(q)))] = v;      // bin c -> DIT position rev8_3(c)
    }
    __syncthreads();
    cplx* Uw = U[w];
    wstage<8,  8,64,true,512>(Uw, tab, lane); WFENCE();
    wstage<8, 64, 8,true,512>(Uw, tab, lane); WFENCE();
    wstage<8,512, 1,true,512>(Uw, tab, lane); WFENCE();
    __syncthreads();                           // store reads across columns
    float* oa = out + (size_t)(2*s)*NS + n2base;
    float* ob = out + (size_t)(2*s+1)*NS + n2base;
#pragma unroll
    for(int k=0;k<8;++k){
        int i = tid + 256*k;
        int n1 = i >> 2, ws = i & 3;
        cplx v = U[ws][PX(n1)];
        oa[n1*500 + ws] = v.x;
        ob[n1*500 + ws] = v.y;
    }
}

// ---------------------------------------------------------------------------
extern "C" void kernel_launch(void* const* d_in, const int* in_sizes, int n_in,
                              void* d_out, int out_size, void* d_ws, size_t ws_size,
                              hipStream_t stream) {
    const float* fm = (const float*)d_in[0];     // (4,500,64)
    const float* noise = (const float*)d_in[1];  // (4,256000)
    float* out = (float*)d_out;

    char* ws = (char*)d_ws;
    cplx*  Y   = (cplx*)ws;                      // 2 signals * 256000 cplx = 4,096,000 B
    float* mmL = (float*)(ws + 4200000);         // mm[4][64] + logff[64]

    kFused1<<<255, 256, 0, stream>>>(fm, noise, mmL, Y);
    kFused2<<<512, 256, 0, stream>>>(Y, mmL);
    kFused3<<<250, 256, 0, stream>>>(Y, out);
}